// Round 9
// baseline (1782.460 us; speedup 1.0000x reference)
//
#include <hip/hip_runtime.h>

namespace {
constexpr int kNB = 16;        // batches
constexpr int kN  = 4096;      // points per batch
constexpr int kD  = 64;        // point feature dim
constexpr int kS  = 1024;      // NPOINT
constexpr int kK  = 32;        // NSAMPLE
constexpr int kG  = kNB * kS;  // 16384 groups
constexpr int C0 = 67, C1 = 64, C2 = 128, C3 = 256;
constexpr float kEps = 1e-5f;
constexpr double kR2d = 0.04000000000000001;  // python 0.2**2 in f64
constexpr float kRowCount = (float)(kG * kK);  // 524288 rows
constexpr int kFT = 256;       // fps threads (4 waves)
constexpr int kFW = kFT / 64;  // fps waves (4)
constexpr int kFP = kN / kFT;  // points per thread (16), CONTIGUOUS chunk
constexpr int kLS = 33;        // padded LDS stride for packed activations
constexpr int kXS = 132;       // padded LDS stride for x2 staging tile (m-major)
// weight fragment array: w0 frags [0,8), w1 frags [8,24), w2 frags [24,88)
constexpr int kNF = 88;
}

typedef __attribute__((ext_vector_type(8))) short short8;  // 8 bf16 (4 VGPRs)
typedef __attribute__((ext_vector_type(4))) float f32x4;   // MFMA acc

// RNE bf16 split: x ~= hi + lo with relative error ~2^-18
__device__ __forceinline__ void split_bf16(float x, unsigned& hi, unsigned& lo) {
  const unsigned u = __float_as_uint(x);
  hi = (u + 0x7fffu + ((u >> 16) & 1u)) >> 16;
  const float rem = x - __uint_as_float(hi << 16);
  const unsigned u2 = __float_as_uint(rem);
  lo = ((u2 + 0x7fffu + ((u2 >> 16) & 1u)) >> 16) & 0xffffu;
}
__device__ __forceinline__ unsigned pack_sb(float x) {
  unsigned hi, lo;
  split_bf16(x, hi, lo);
  return (hi << 16) | lo;
}
__device__ __forceinline__ float unpack_sb(unsigned pk) {
  return __uint_as_float(pk & 0xffff0000u) + __uint_as_float(pk << 16);
}

// triple-MFMA split-bf16 product: acc += A*B with ~fp32 accuracy
__device__ __forceinline__ f32x4 mfma3(const short8& ah, const short8& al,
                                       const unsigned short* __restrict__ whiF,
                                       const unsigned short* __restrict__ wloF,
                                       size_t fb, f32x4 acc) {
  const short8 bh = *(const short8*)(whiF + fb);
  const short8 bl = *(const short8*)(wloF + fb);
  acc = __builtin_amdgcn_mfma_f32_16x16x32_bf16(ah, bh, acc, 0, 0, 0);
  acc = __builtin_amdgcn_mfma_f32_16x16x32_bf16(ah, bl, acc, 0, 0, 0);
  acc = __builtin_amdgcn_mfma_f32_16x16x32_bf16(al, bh, acc, 0, 0, 0);
  return acc;
}

// load A-fragment (16x16x32, A[m=l15][k=quad*8+j]) from packed LDS
__device__ __forceinline__ void load_afrag(const unsigned* p, int k0, int mbase,
                                           int quad, int l15, short8& hi, short8& lo) {
#pragma unroll
  for (int j = 0; j < 8; ++j) {
    const unsigned pk = p[(k0 + quad * 8 + j) * kLS + mbase + l15];
    hi[j] = (short)(pk >> 16);
    lo[j] = (short)(pk & 0xffffu);
  }
}

// ------------------------------------------------------------------
// 4-value candidate DPP reduce step: moves (val,x,y,z) from source
// lanes per CTRL/RM; take incoming on val >= (incoming always comes
// from a LOWER lane in this sequence -> ties resolve to smaller index).
// Inactive rows / row-edge lanes receive their own value (old=src) ->
// no-op. After the 6-step sequence lane 63 holds the wave winner.
// ------------------------------------------------------------------
template <int CTRL, int RM>
__device__ __forceinline__ void dpp_cand_step(float& v, float& x, float& y, float& z) {
  const float nv = __int_as_float(__builtin_amdgcn_update_dpp(
      __float_as_int(v), __float_as_int(v), CTRL, RM, 0xf, false));
  const float nx = __int_as_float(__builtin_amdgcn_update_dpp(
      __float_as_int(x), __float_as_int(x), CTRL, RM, 0xf, false));
  const float ny = __int_as_float(__builtin_amdgcn_update_dpp(
      __float_as_int(y), __float_as_int(y), CTRL, RM, 0xf, false));
  const float nz = __int_as_float(__builtin_amdgcn_update_dpp(
      __float_as_int(z), __float_as_int(z), CTRL, RM, 0xf, false));
  const bool take = (nv >= v);   // incoming = lower lane; ties -> lower lane
  v = take ? nv : v;
  x = take ? nx : x;
  y = take ? ny : y;
  z = take ? nz : z;
}
__device__ __forceinline__ void wave_cand_dpp(float& v, float& x, float& y, float& z) {
  dpp_cand_step<0x111, 0xf>(v, x, y, z);  // row_shr:1
  dpp_cand_step<0x112, 0xf>(v, x, y, z);  // row_shr:2
  dpp_cand_step<0x114, 0xf>(v, x, y, z);  // row_shr:4
  dpp_cand_step<0x118, 0xf>(v, x, y, z);  // row_shr:8
  dpp_cand_step<0x142, 0xa>(v, x, y, z);  // row_bcast:15 -> rows 1,3
  dpp_cand_step<0x143, 0xc>(v, x, y, z);  // row_bcast:31 -> rows 2,3
}

// ------------------------------------------------------------------
// FPS: 256 threads (4 waves), 16 CONTIGUOUS points/thread.
// Coordinates travel WITH the max through a 4-value DPP reduce; lane 63
// publishes one float4 per wave; post-barrier scan yields the centroid
// directly (no ballot/readlane chain, no dependent LDS point lookup,
// no 48 KB SoA). __launch_bounds__(.,1) grants the full VGPR budget so
// the 64-float point arrays stay in registers (R6's regression was a
// spill at VGPR=60). Selection arithmetic bit-identical to R2..R8:
// contract-off, d = dx*dx + dy*dy; d = d + dz*dz; fmin; strict > in
// lane (smallest j), >=-toward-lower-lane across lanes, strict > across
// waves => np.argmax smallest-index tie-break.
// ------------------------------------------------------------------
__global__ __launch_bounds__(kFT, 1) void fps_kernel(const float* __restrict__ xyz,
                                                     float* __restrict__ new_xyz) {
#pragma clang fp contract(off)
  const int b = blockIdx.x;
  const int tid = threadIdx.x;
  const int w = tid >> 6;
  const int lane = tid & 63;
  const float* xb = xyz + (size_t)b * kN * 3;

  __shared__ float sout[kS * 3];             // 12 KB staged output
  __shared__ float4 pB[2][kFW];              // per-wave (val,x,y,z), parity-buffered

  float px[kFP], py[kFP], pz[kFP], dist[kFP];
#pragma unroll
  for (int j = 0; j < kFP; ++j) {
    const int p = tid * kFP + j;               // contiguous chunk
    px[j] = xb[p * 3 + 0];
    py[j] = xb[p * 3 + 1];
    pz[j] = xb[p * 3 + 2];
    dist[j] = 1e10f;
  }
  float cx = xb[0], cy = xb[1], cz = xb[2];  // farthest starts at index 0

  for (int t = 0; t < kS; ++t) {
    if (tid == 0) {
      sout[t * 3 + 0] = cx; sout[t * 3 + 1] = cy; sout[t * 3 + 2] = cz;
    }
    // --- update + per-lane argmax (strict > keeps smallest j)
    float lv = -1.0f, bx = 0.f, by = 0.f, bz = 0.f;
#pragma unroll
    for (int j = 0; j < kFP; ++j) {
      const float dx = px[j] - cx, dy = py[j] - cy, dz = pz[j] - cz;
      float d = dx * dx + dy * dy;
      d = d + dz * dz;
      const float dd = fminf(dist[j], d);
      dist[j] = dd;
      if (dd > lv) { lv = dd; bx = px[j]; by = py[j]; bz = pz[j]; }
    }
    // --- wave-level candidate reduce (VALU pipe only)
    wave_cand_dpp(lv, bx, by, bz);
    const int par = t & 1;
    if (lane == 63) pB[par][w] = make_float4(lv, bx, by, bz);
    __syncthreads();
    float4 best = pB[par][0];
#pragma unroll
    for (int k = 1; k < kFW; ++k) {
      const float4 o = pB[par][k];
      if (o.x > best.x) best = o;              // tie -> earlier wave = smaller idx
    }
    cx = best.y; cy = best.z; cz = best.w;
  }
  __syncthreads();
  float* ob = new_xyz + (size_t)b * kS * 3;
  for (int e = tid; e < kS * 3; e += kFT) ob[e] = sout[e];  // coalesced once
}

// ------------------------------------------------------------------
// Ball query (unchanged)
// ------------------------------------------------------------------
__global__ __launch_bounds__(256) void ball_kernel(const float* __restrict__ xyz,
                                                   const float* __restrict__ new_xyz,
                                                   int* __restrict__ idx) {
  const int g = blockIdx.x * 4 + (threadIdx.x >> 6);
  const int lane = threadIdx.x & 63;
  const int b = g >> 10;
  const float* xb = xyz + (size_t)b * kN * 3;
  const double sx = (double)new_xyz[(size_t)g * 3 + 0];
  const double sy = (double)new_xyz[(size_t)g * 3 + 1];
  const double sz = (double)new_xyz[(size_t)g * 3 + 2];
  const double s2 = sx * sx + sy * sy + sz * sz;
  int have = 0, first = -1;
  int* out = idx + (size_t)g * kK;
  for (int c = 0; c < kN; c += 64) {
    const int p = c + lane;
    const double px = (double)xb[p * 3 + 0];
    const double py = (double)xb[p * 3 + 1];
    const double pz = (double)xb[p * 3 + 2];
    const double p2 = px * px + py * py + pz * pz;
    const double dot = sx * px + sy * py + sz * pz;
    const double d = -2.0 * dot + s2 + p2;
    const bool elig = !(d > kR2d);
    const unsigned long long mask = __ballot(elig);
    if (first < 0 && mask) first = c + __builtin_ctzll(mask);
    const int pos = have + __popcll(mask & ((1ull << lane) - 1ull));
    if (elig && pos < kK) out[pos] = p;
    have += __popcll(mask);
    if (have >= kK) break;
  }
  if (have < kK) {
    if (lane >= have && lane < kK) out[lane] = first;
  }
}

// ------------------------------------------------------------------
// Split w0/w1/w2 into B-fragment-ordered (hi,lo) arrays (unchanged)
// ------------------------------------------------------------------
__global__ __launch_bounds__(256) void wsplit_kernel(const float* __restrict__ w0,
                                                     const float* __restrict__ w1,
                                                     const float* __restrict__ w2,
                                                     unsigned short* __restrict__ whiF,
                                                     unsigned short* __restrict__ wloF) {
  const int gid = blockIdx.x * 256 + threadIdx.x;   // 88*64 = 5632 total
  const int lane = gid & 63;
  const int f = gid >> 6;
  const int quad = lane >> 4, l15 = lane & 15;
  const float* src;
  int kt, nt, nstride;
  if (f < 8) { src = w0; kt = f >> 2; nt = f & 3; nstride = C1; }
  else if (f < 24) { const int fl = f - 8; src = w1; kt = fl >> 3; nt = fl & 7; nstride = C2; }
  else { const int fl = f - 24; src = w2; kt = fl >> 4; nt = fl & 15; nstride = C3; }
  const int k0 = kt * 32 + quad * 8;
  const int n = nt * 16 + l15;
#pragma unroll
  for (int j = 0; j < 8; ++j) {
    const float x = src[(size_t)(k0 + j) * nstride + n];
    unsigned hi, lo;
    split_bf16(x, hi, lo);
    whiF[(size_t)gid * 8 + j] = (unsigned short)hi;
    wloF[(size_t)gid * 8 + j] = (unsigned short)lo;
  }
}

// ------------------------------------------------------------------
// gather (VECTORIZED): points part via float4 — 16 consecutive lanes
// read one sample's contiguous 64-float row (256 B segments).
// ------------------------------------------------------------------
__device__ __forceinline__ void gather_packed(int g, const float* __restrict__ xyz,
                                              const float* __restrict__ points,
                                              const float* __restrict__ new_xyz,
                                              const int* __restrict__ idx,
                                              unsigned* fsp) {
  const int b = g >> 10;
  const float* xb = xyz + (size_t)b * kN * 3;
  const float* pb = points + (size_t)b * kN * kD;
  const int* ig = idx + (size_t)g * kK;
  const int tid = threadIdx.x;
#pragma unroll
  for (int it = 0; it < 2; ++it) {
    const int e = tid + it * 256;          // 512 items: (r, c4)
    const int r = e >> 4, c4 = e & 15;
    const int i = ig[r];
    const float4 v = *(const float4*)(pb + (size_t)i * kD + c4 * 4);
    const int cb = 3 + c4 * 4;
    fsp[(cb + 0) * kLS + r] = pack_sb(v.x);
    fsp[(cb + 1) * kLS + r] = pack_sb(v.y);
    fsp[(cb + 2) * kLS + r] = pack_sb(v.z);
    fsp[(cb + 3) * kLS + r] = pack_sb(v.w);
  }
  if (tid < 96) {
    const int c = tid >> 5, r = tid & 31;
    const int i = ig[r];
    const float v = xb[i * 3 + c] - new_xyz[(size_t)g * 3 + c];
    fsp[c * kLS + r] = pack_sb(v);
  }
}

// L1 via MFMA: K=64 through matrix cores + channels 64..66 VALU tail.
__device__ __forceinline__ void l1_mfma(const unsigned* fsp,
                                        const unsigned short* __restrict__ whiF,
                                        const unsigned short* __restrict__ wloF,
                                        const float* __restrict__ w0,
                                        const float* __restrict__ b0,
                                        int mt, int nh, int quad, int l15, int lane,
                                        f32x4 out[2]) {
  short8 ah[2], al[2];
#pragma unroll
  for (int ks = 0; ks < 2; ++ks)
    load_afrag(fsp, ks * 32, mt * 16, quad, l15, ah[ks], al[ks]);
#pragma unroll
  for (int nt2 = 0; nt2 < 2; ++nt2) {
    const int nt = nh * 2 + nt2;
    const int n = nt * 16 + l15;
    f32x4 acc = {0.f, 0.f, 0.f, 0.f};
#pragma unroll
    for (int ks = 0; ks < 2; ++ks)
      acc = mfma3(ah[ks], al[ks], whiF, wloF, ((size_t)(ks * 4 + nt) * 64 + lane) * 8, acc);
#pragma unroll
    for (int c = 64; c < 67; ++c) {
      const float wv0 = w0[(size_t)c * C1 + n];
#pragma unroll
      for (int r = 0; r < 4; ++r) {
        const float x = unpack_sb(fsp[c * kLS + mt * 16 + quad * 4 + r]);
        acc[r] += x * wv0;
      }
    }
    const float bb = b0[n];
#pragma unroll
    for (int r = 0; r < 4; ++r) acc[r] += bb;
    out[nt2] = acc;
  }
}

// ------------------------------------------------------------------
// stats1: gather + L1(MFMA) -> per-channel sum/sumsq partials
// ------------------------------------------------------------------
__global__ __launch_bounds__(256) void stats1_kernel(
    const float* __restrict__ xyz, const float* __restrict__ points,
    const float* __restrict__ new_xyz, const int* __restrict__ idx,
    const float* __restrict__ w0, const float* __restrict__ b0,
    const unsigned short* __restrict__ whiF, const unsigned short* __restrict__ wloF,
    float* __restrict__ P) {
  __shared__ unsigned fsp[C0 * kLS];
  __shared__ float redS[C1 * 2], redQ[C1 * 2];
  const int g = blockIdx.x;
  const int tid = threadIdx.x;
  gather_packed(g, xyz, points, new_xyz, idx, fsp);
  __syncthreads();
  const int wv = tid >> 6, lane = tid & 63;
  const int mt = wv & 1, nh = wv >> 1;
  const int quad = lane >> 4, l15 = lane & 15;
  f32x4 acc1[2];
  l1_mfma(fsp, whiF, wloF, w0, b0, mt, nh, quad, l15, lane, acc1);
#pragma unroll
  for (int nt2 = 0; nt2 < 2; ++nt2) {
    const int n = (nh * 2 + nt2) * 16 + l15;
    const f32x4 a = acc1[nt2];
    float s = a[0] + a[1] + a[2] + a[3];
    float q = a[0] * a[0] + a[1] * a[1] + a[2] * a[2] + a[3] * a[3];
    s += __shfl_xor(s, 16); s += __shfl_xor(s, 32);
    q += __shfl_xor(q, 16); q += __shfl_xor(q, 32);
    if (quad == 0) { redS[n * 2 + mt] = s; redQ[n * 2 + mt] = q; }
  }
  __syncthreads();
  if (tid < C1) {
    P[(size_t)g * 2 * C1 + tid] = redS[tid * 2] + redS[tid * 2 + 1];
    P[(size_t)g * 2 * C1 + C1 + tid] = redQ[tid * 2] + redQ[tid * 2 + 1];
  }
}

// ------------------------------------------------------------------
// stats2: gather + L1(MFMA) + BN0/relu/pack + L2(MFMA) -> partials.
// If x2p != nullptr, also persist packed pre-BN L2 output (x2).
// ------------------------------------------------------------------
__global__ __launch_bounds__(256) void stats2_kernel(
    const float* __restrict__ xyz, const float* __restrict__ points,
    const float* __restrict__ new_xyz, const int* __restrict__ idx,
    const float* __restrict__ w0, const float* __restrict__ b0, const float* __restrict__ ab0,
    const float* __restrict__ b1,
    const unsigned short* __restrict__ whiF, const unsigned short* __restrict__ wloF,
    float* __restrict__ P, unsigned* __restrict__ x2p) {
  __shared__ unsigned fsp[C0 * kLS];
  __shared__ unsigned y1p[C1 * kLS];
  __shared__ unsigned x2s[32 * kXS];
  __shared__ float redS[C2 * 2], redQ[C2 * 2];
  const int g = blockIdx.x;
  const int tid = threadIdx.x;
  gather_packed(g, xyz, points, new_xyz, idx, fsp);
  __syncthreads();
  const int wv = tid >> 6, lane = tid & 63;
  const int mt = wv & 1, nh = wv >> 1;
  const int quad = lane >> 4, l15 = lane & 15;
  {
    f32x4 acc1[2];
    l1_mfma(fsp, whiF, wloF, w0, b0, mt, nh, quad, l15, lane, acc1);
#pragma unroll
    for (int nt2 = 0; nt2 < 2; ++nt2) {
      const int n = (nh * 2 + nt2) * 16 + l15;
      const float a = ab0[n * 2 + 0], c = ab0[n * 2 + 1];
#pragma unroll
      for (int r = 0; r < 4; ++r) {
        const float y = fmaxf(acc1[nt2][r] * a + c, 0.f);
        y1p[n * kLS + mt * 16 + quad * 4 + r] = pack_sb(y);
      }
    }
  }
  __syncthreads();
  {
    short8 ah[2], al[2];
#pragma unroll
    for (int ks = 0; ks < 2; ++ks)
      load_afrag(y1p, ks * 32, mt * 16, quad, l15, ah[ks], al[ks]);
#pragma unroll
    for (int nt2 = 0; nt2 < 4; ++nt2) {
      const int nt = nh * 4 + nt2;
      const int n = nt * 16 + l15;
      f32x4 acc = {0.f, 0.f, 0.f, 0.f};
#pragma unroll
      for (int ks = 0; ks < 2; ++ks)
        acc = mfma3(ah[ks], al[ks], whiF, wloF, ((size_t)(8 + ks * 8 + nt) * 64 + lane) * 8, acc);
      const float bb = b1[n];
      const float v0 = acc[0] + bb, v1 = acc[1] + bb, v2 = acc[2] + bb, v3 = acc[3] + bb;
      if (x2p) {
        const int m0 = mt * 16 + quad * 4;
        x2s[(m0 + 0) * kXS + n] = pack_sb(v0);
        x2s[(m0 + 1) * kXS + n] = pack_sb(v1);
        x2s[(m0 + 2) * kXS + n] = pack_sb(v2);
        x2s[(m0 + 3) * kXS + n] = pack_sb(v3);
      }
      float s = v0 + v1 + v2 + v3;
      float q = v0 * v0 + v1 * v1 + v2 * v2 + v3 * v3;
      s += __shfl_xor(s, 16); s += __shfl_xor(s, 32);
      q += __shfl_xor(q, 16); q += __shfl_xor(q, 32);
      if (quad == 0) { redS[n * 2 + mt] = s; redQ[n * 2 + mt] = q; }
    }
  }
  __syncthreads();
  if (x2p) {
#pragma unroll
    for (int i = 0; i < 16; ++i) {
      const int f = tid + i * 256;
      const int m = f >> 7, n = f & 127;
      x2p[(size_t)g * 4096 + f] = x2s[m * kXS + n];   // coalesced 256B/wave
    }
  }
  if (tid < C2) {
    P[(size_t)g * 2 * C2 + tid] = redS[tid * 2] + redS[tid * 2 + 1];
    P[(size_t)g * 2 * C2 + C2 + tid] = redQ[tid * 2] + redQ[tid * 2 + 1];
  }
}

// ------------------------------------------------------------------
// stats3 (FALLBACK): gather + L1 + L2 + L3 all via MFMA
// ------------------------------------------------------------------
__global__ __launch_bounds__(256) void stats3_kernel(
    const float* __restrict__ xyz, const float* __restrict__ points,
    const float* __restrict__ new_xyz, const int* __restrict__ idx,
    const float* __restrict__ w0, const float* __restrict__ b0, const float* __restrict__ ab0,
    const float* __restrict__ b1, const float* __restrict__ ab1,
    const float* __restrict__ b2,
    const unsigned short* __restrict__ whiF, const unsigned short* __restrict__ wloF,
    float* __restrict__ P, float* __restrict__ maxv, float* __restrict__ minv) {
  __shared__ unsigned fsp[C0 * kLS];
  __shared__ unsigned y1p[C1 * kLS];
  __shared__ unsigned y2p[C2 * kLS];
  __shared__ float redS[C3 * 2], redQ[C3 * 2], redM[C3 * 2], redN[C3 * 2];
  const int g = blockIdx.x;
  const int tid = threadIdx.x;
  gather_packed(g, xyz, points, new_xyz, idx, fsp);
  __syncthreads();
  const int wv = tid >> 6, lane = tid & 63;
  const int mt = wv & 1, nh = wv >> 1;
  const int quad = lane >> 4, l15 = lane & 15;
  {
    f32x4 acc1[2];
    l1_mfma(fsp, whiF, wloF, w0, b0, mt, nh, quad, l15, lane, acc1);
#pragma unroll
    for (int nt2 = 0; nt2 < 2; ++nt2) {
      const int n = (nh * 2 + nt2) * 16 + l15;
      const float a = ab0[n * 2 + 0], c = ab0[n * 2 + 1];
#pragma unroll
      for (int r = 0; r < 4; ++r) {
        const float y = fmaxf(acc1[nt2][r] * a + c, 0.f);
        y1p[n * kLS + mt * 16 + quad * 4 + r] = pack_sb(y);
      }
    }
  }
  __syncthreads();
  {
    short8 ah[2], al[2];
#pragma unroll
    for (int ks = 0; ks < 2; ++ks)
      load_afrag(y1p, ks * 32, mt * 16, quad, l15, ah[ks], al[ks]);
#pragma unroll
    for (int nt2 = 0; nt2 < 4; ++nt2) {
      const int nt = nh * 4 + nt2;
      const int n = nt * 16 + l15;
      f32x4 acc = {0.f, 0.f, 0.f, 0.f};
#pragma unroll
      for (int ks = 0; ks < 2; ++ks)
        acc = mfma3(ah[ks], al[ks], whiF, wloF, ((size_t)(8 + ks * 8 + nt) * 64 + lane) * 8, acc);
      const float bb = b1[n];
      const float a = ab1[n * 2 + 0], c = ab1[n * 2 + 1];
#pragma unroll
      for (int r = 0; r < 4; ++r) {
        const float y = fmaxf((acc[r] + bb) * a + c, 0.f);
        y2p[n * kLS + mt * 16 + quad * 4 + r] = pack_sb(y);
      }
    }
  }
  __syncthreads();
  {
    short8 ah[4], al[4];
#pragma unroll
    for (int ks = 0; ks < 4; ++ks)
      load_afrag(y2p, ks * 32, mt * 16, quad, l15, ah[ks], al[ks]);
#pragma unroll
    for (int nt2 = 0; nt2 < 8; ++nt2) {
      const int nt = nh * 8 + nt2;
      f32x4 acc = {0.f, 0.f, 0.f, 0.f};
#pragma unroll
      for (int ks = 0; ks < 4; ++ks)
        acc = mfma3(ah[ks], al[ks], whiF, wloF, ((size_t)(24 + ks * 16 + nt) * 64 + lane) * 8, acc);
      const int n = nt * 16 + l15;
      const float bn = b2[n];
      const float v0 = acc[0] + bn, v1 = acc[1] + bn, v2 = acc[2] + bn, v3 = acc[3] + bn;
      float s = v0 + v1 + v2 + v3;
      float q = v0 * v0 + v1 * v1 + v2 * v2 + v3 * v3;
      float mx = fmaxf(fmaxf(v0, v1), fmaxf(v2, v3));
      float mn = fminf(fminf(v0, v1), fminf(v2, v3));
      s += __shfl_xor(s, 16); s += __shfl_xor(s, 32);
      q += __shfl_xor(q, 16); q += __shfl_xor(q, 32);
      mx = fmaxf(mx, __shfl_xor(mx, 16)); mx = fmaxf(mx, __shfl_xor(mx, 32));
      mn = fminf(mn, __shfl_xor(mn, 16)); mn = fminf(mn, __shfl_xor(mn, 32));
      if (quad == 0) {
        redS[n * 2 + mt] = s; redQ[n * 2 + mt] = q;
        redM[n * 2 + mt] = mx; redN[n * 2 + mt] = mn;
      }
    }
  }
  __syncthreads();
  {
    const int ch = tid;
    P[(size_t)g * 2 * C3 + ch] = redS[ch * 2] + redS[ch * 2 + 1];
    P[(size_t)g * 2 * C3 + C3 + ch] = redQ[ch * 2] + redQ[ch * 2 + 1];
    maxv[(size_t)g * C3 + ch] = fmaxf(redM[ch * 2], redM[ch * 2 + 1]);
    minv[(size_t)g * C3 + ch] = fminf(redN[ch * 2], redN[ch * 2 + 1]);
  }
}

// ------------------------------------------------------------------
// stats3p (PERSIST): read packed x2, BN1+relu -> y2p LDS, then L3
// via MFMA; partials + fused maxpool.
// ------------------------------------------------------------------
__global__ __launch_bounds__(256) void stats3p_kernel(
    const unsigned* __restrict__ x2p, const float* __restrict__ ab1,
    const float* __restrict__ b2,
    const unsigned short* __restrict__ whiF, const unsigned short* __restrict__ wloF,
    float* __restrict__ P, float* __restrict__ maxv, float* __restrict__ minv) {
  __shared__ unsigned y2p[C2 * kLS];
  __shared__ float sab[2 * C2];
  __shared__ float redS[C3 * 2], redQ[C3 * 2], redM[C3 * 2], redN[C3 * 2];
  const int g = blockIdx.x;
  const int tid = threadIdx.x;
  sab[tid] = ab1[tid];            // 256 floats = 2*C2
  __syncthreads();
#pragma unroll
  for (int i = 0; i < 16; ++i) {
    const int f = tid + i * 256;
    const int m = f >> 7, n = f & 127;
    const unsigned pk = x2p[(size_t)g * 4096 + f];   // coalesced 256B/wave
    const float x = unpack_sb(pk);
    const float y = fmaxf(x * sab[n * 2 + 0] + sab[n * 2 + 1], 0.f);
    y2p[n * kLS + m] = pack_sb(y);
  }
  __syncthreads();
  const int wv = tid >> 6, lane = tid & 63;
  const int mt = wv & 1, nh = wv >> 1;
  const int quad = lane >> 4, l15 = lane & 15;
  {
    short8 ah[4], al[4];
#pragma unroll
    for (int ks = 0; ks < 4; ++ks)
      load_afrag(y2p, ks * 32, mt * 16, quad, l15, ah[ks], al[ks]);
#pragma unroll
    for (int nt2 = 0; nt2 < 8; ++nt2) {
      const int nt = nh * 8 + nt2;
      f32x4 acc = {0.f, 0.f, 0.f, 0.f};
#pragma unroll
      for (int ks = 0; ks < 4; ++ks)
        acc = mfma3(ah[ks], al[ks], whiF, wloF, ((size_t)(24 + ks * 16 + nt) * 64 + lane) * 8, acc);
      const int n = nt * 16 + l15;
      const float bn = b2[n];
      const float v0 = acc[0] + bn, v1 = acc[1] + bn, v2 = acc[2] + bn, v3 = acc[3] + bn;
      float s = v0 + v1 + v2 + v3;
      float q = v0 * v0 + v1 * v1 + v2 * v2 + v3 * v3;
      float mx = fmaxf(fmaxf(v0, v1), fmaxf(v2, v3));
      float mn = fminf(fminf(v0, v1), fminf(v2, v3));
      s += __shfl_xor(s, 16); s += __shfl_xor(s, 32);
      q += __shfl_xor(q, 16); q += __shfl_xor(q, 32);
      mx = fmaxf(mx, __shfl_xor(mx, 16)); mx = fmaxf(mx, __shfl_xor(mx, 32));
      mn = fminf(mn, __shfl_xor(mn, 16)); mn = fminf(mn, __shfl_xor(mn, 32));
      if (quad == 0) {
        redS[n * 2 + mt] = s; redQ[n * 2 + mt] = q;
        redM[n * 2 + mt] = mx; redN[n * 2 + mt] = mn;
      }
    }
  }
  __syncthreads();
  {
    const int ch = tid;
    P[(size_t)g * 2 * C3 + ch] = redS[ch * 2] + redS[ch * 2 + 1];
    P[(size_t)g * 2 * C3 + C3 + ch] = redQ[ch * 2] + redQ[ch * 2 + 1];
    maxv[(size_t)g * C3 + ch] = fmaxf(redM[ch * 2], redM[ch * 2 + 1]);
    minv[(size_t)g * C3 + ch] = fminf(redN[ch * 2], redN[ch * 2 + 1]);
  }
}

// ------------------------------------------------------------------
// reduce / final (unchanged)
// ------------------------------------------------------------------
__global__ __launch_bounds__(256) void reduce_kernel(const float* __restrict__ P, int CH,
                                                     const float* __restrict__ gamma,
                                                     const float* __restrict__ beta,
                                                     float* __restrict__ ab) {
  const int ch = blockIdx.x;
  float s = 0.f, q = 0.f;
  for (int i = threadIdx.x; i < kG; i += 256) {
    s += P[(size_t)i * 2 * CH + ch];
    q += P[(size_t)i * 2 * CH + CH + ch];
  }
#pragma unroll
  for (int off = 32; off > 0; off >>= 1) {
    s += __shfl_down(s, off);
    q += __shfl_down(q, off);
  }
  __shared__ float ss[4], qs[4];
  if ((threadIdx.x & 63) == 0) { ss[threadIdx.x >> 6] = s; qs[threadIdx.x >> 6] = q; }
  __syncthreads();
  if (threadIdx.x == 0) {
    s = ss[0] + ss[1] + ss[2] + ss[3];
    q = qs[0] + qs[1] + qs[2] + qs[3];
    const float mean = s / kRowCount;
    float var = q / kRowCount - mean * mean;
    var = fmaxf(var, 0.f);
    const float a = gamma[ch] * (1.0f / sqrtf(var + kEps));
    const float c = beta[ch] - mean * a;
    ab[ch * 2 + 0] = a;
    ab[ch * 2 + 1] = c;
  }
}

__global__ __launch_bounds__(256) void final_kernel(const float* __restrict__ ab2,
                                                    const float* __restrict__ maxv,
                                                    const float* __restrict__ minv,
                                                    float* __restrict__ out) {
  const int e = blockIdx.x * 256 + threadIdx.x;
  const int ch = e & (C3 - 1);
  const float a = ab2[ch * 2 + 0];
  const float c = ab2[ch * 2 + 1];
  const float m = (a >= 0.f) ? maxv[e] : minv[e];
  out[e] = fmaxf(a * m + c, 0.f);
}

extern "C" void kernel_launch(void* const* d_in, const int* in_sizes, int n_in,
                              void* d_out, int out_size, void* d_ws, size_t ws_size,
                              hipStream_t stream) {
  const float* xyz = (const float*)d_in[0];
  const float* points = (const float*)d_in[1];
  const float* w0 = (const float*)d_in[2];
  const float* b0 = (const float*)d_in[3];
  const float* g0 = (const float*)d_in[4];
  const float* bt0 = (const float*)d_in[5];
  const float* w1 = (const float*)d_in[6];
  const float* b1 = (const float*)d_in[7];
  const float* g1 = (const float*)d_in[8];
  const float* bt1 = (const float*)d_in[9];
  const float* w2 = (const float*)d_in[10];
  const float* b2 = (const float*)d_in[11];
  const float* g2 = (const float*)d_in[12];
  const float* bt2 = (const float*)d_in[13];

  float* out_xyz = (float*)d_out;               // (16,1024,3)
  float* out_pts = out_xyz + (size_t)kG * 3;    // (16,1024,256)

  char* ws = (char*)d_ws;
  int* idx = (int*)ws;                                      // 2 MB
  float* P = (float*)(ws + (size_t)kG * kK * sizeof(int));  // 33.5 MB (sized for C3)
  float* maxv = P + (size_t)kG * 2 * C3;                    // 16.8 MB
  float* minv = maxv + (size_t)kG * C3;                     // 16.8 MB
  float* ab0 = minv + (size_t)kG * C3;
  float* ab1 = ab0 + 2 * C1;
  float* ab2 = ab1 + 2 * C2;
  unsigned short* whiF = (unsigned short*)(ab2 + 2 * C3);   // 88 KB (16B aligned)
  unsigned short* wloF = whiF + (size_t)kNF * 512;          // 88 KB
  unsigned* x2p = (unsigned*)(wloF + (size_t)kNF * 512);    // 268 MB (optional)
  const size_t needed = (size_t)((char*)(x2p + (size_t)kG * 4096) - ws);
  const bool persist = ws_size >= needed;                    // constant across calls
  unsigned* x2arg = persist ? x2p : nullptr;

  wsplit_kernel<<<kNF / 4, 256, 0, stream>>>(w0, w1, w2, whiF, wloF);
  fps_kernel<<<kNB, kFT, 0, stream>>>(xyz, out_xyz);
  ball_kernel<<<kG / 4, 256, 0, stream>>>(xyz, out_xyz, idx);
  stats1_kernel<<<kG, 256, 0, stream>>>(xyz, points, out_xyz, idx, w0, b0, whiF, wloF, P);
  reduce_kernel<<<C1, 256, 0, stream>>>(P, C1, g0, bt0, ab0);
  stats2_kernel<<<kG, 256, 0, stream>>>(xyz, points, out_xyz, idx, w0, b0, ab0, b1,
                                        whiF, wloF, P, x2arg);
  reduce_kernel<<<C2, 256, 0, stream>>>(P, C2, g1, bt1, ab1);
  if (persist) {
    stats3p_kernel<<<kG, 256, 0, stream>>>(x2p, ab1, b2, whiF, wloF, P, maxv, minv);
  } else {
    stats3_kernel<<<kG, 256, 0, stream>>>(xyz, points, out_xyz, idx, w0, b0, ab0,
                                          b1, ab1, b2, whiF, wloF, P, maxv, minv);
  }
  reduce_kernel<<<C3, 256, 0, stream>>>(P, C3, g2, bt2, ab2);
  final_kernel<<<(kG * C3) / 256, 256, 0, stream>>>(ab2, maxv, minv, out_pts);
}

// Round 10
// 1382.975 us; speedup vs baseline: 1.2889x; 1.2889x over previous
//
#include <hip/hip_runtime.h>

namespace {
constexpr int kNB = 16;        // batches
constexpr int kN  = 4096;      // points per batch
constexpr int kD  = 64;        // point feature dim
constexpr int kS  = 1024;      // NPOINT
constexpr int kK  = 32;        // NSAMPLE
constexpr int kG  = kNB * kS;  // 16384 groups
constexpr int C0 = 67, C1 = 64, C2 = 128, C3 = 256;
constexpr float kEps = 1e-5f;
constexpr double kR2d = 0.04000000000000001;  // python 0.2**2 in f64
constexpr float kRowCount = (float)(kG * kK);  // 524288 rows
constexpr int kFT = 512;       // fps threads (8 waves)
constexpr int kFW = kFT / 64;  // fps waves (8)
constexpr int kFP = kN / kFT;  // points per thread (8), CONTIGUOUS chunk
constexpr int kLS = 33;        // padded LDS stride for packed activations
constexpr int kXS = 132;       // padded LDS stride for x2 staging tile (m-major)
constexpr int kX1S = 66;       // padded LDS stride for x1 staging tile (m-major)
// weight fragment array: w0 frags [0,8), w1 frags [8,24), w2 frags [24,88)
constexpr int kNF = 88;
}

typedef __attribute__((ext_vector_type(8))) short short8;  // 8 bf16 (4 VGPRs)
typedef __attribute__((ext_vector_type(4))) float f32x4;   // MFMA acc

// RNE bf16 split: x ~= hi + lo with relative error ~2^-18
__device__ __forceinline__ void split_bf16(float x, unsigned& hi, unsigned& lo) {
  const unsigned u = __float_as_uint(x);
  hi = (u + 0x7fffu + ((u >> 16) & 1u)) >> 16;
  const float rem = x - __uint_as_float(hi << 16);
  const unsigned u2 = __float_as_uint(rem);
  lo = ((u2 + 0x7fffu + ((u2 >> 16) & 1u)) >> 16) & 0xffffu;
}
__device__ __forceinline__ unsigned pack_sb(float x) {
  unsigned hi, lo;
  split_bf16(x, hi, lo);
  return (hi << 16) | lo;
}
__device__ __forceinline__ float unpack_sb(unsigned pk) {
  return __uint_as_float(pk & 0xffff0000u) + __uint_as_float(pk << 16);
}

// triple-MFMA split-bf16 product: acc += A*B with ~fp32 accuracy
__device__ __forceinline__ f32x4 mfma3(const short8& ah, const short8& al,
                                       const unsigned short* __restrict__ whiF,
                                       const unsigned short* __restrict__ wloF,
                                       size_t fb, f32x4 acc) {
  const short8 bh = *(const short8*)(whiF + fb);
  const short8 bl = *(const short8*)(wloF + fb);
  acc = __builtin_amdgcn_mfma_f32_16x16x32_bf16(ah, bh, acc, 0, 0, 0);
  acc = __builtin_amdgcn_mfma_f32_16x16x32_bf16(ah, bl, acc, 0, 0, 0);
  acc = __builtin_amdgcn_mfma_f32_16x16x32_bf16(al, bh, acc, 0, 0, 0);
  return acc;
}

// load A-fragment (16x16x32, A[m=l15][k=quad*8+j]) from packed LDS
__device__ __forceinline__ void load_afrag(const unsigned* p, int k0, int mbase,
                                           int quad, int l15, short8& hi, short8& lo) {
#pragma unroll
  for (int j = 0; j < 8; ++j) {
    const unsigned pk = p[(k0 + quad * 8 + j) * kLS + mbase + l15];
    hi[j] = (short)(pk >> 16);
    lo[j] = (short)(pk & 0xffffu);
  }
}

// DPP-based wave64 max: VALU-pipe only (no ds_bpermute latency chain).
template <int CTRL, int RM>
__device__ __forceinline__ float dpp_max_step(float v) {
  const int vi = __float_as_int(v);
  const int sh = __builtin_amdgcn_update_dpp(vi, vi, CTRL, RM, 0xf, false);
  return fmaxf(v, __int_as_float(sh));
}
__device__ __forceinline__ float wave_max_dpp(float v) {
  v = dpp_max_step<0x111, 0xf>(v);  // row_shr:1
  v = dpp_max_step<0x112, 0xf>(v);  // row_shr:2
  v = dpp_max_step<0x114, 0xf>(v);  // row_shr:4
  v = dpp_max_step<0x118, 0xf>(v);  // row_shr:8
  v = dpp_max_step<0x142, 0xa>(v);  // row_bcast:15 -> rows 1,3
  v = dpp_max_step<0x143, 0xc>(v);  // row_bcast:31 -> rows 2,3
  return v;                          // lane 63 = wave max
}

// ------------------------------------------------------------------
// FPS: 512 threads (8 waves), 8 CONTIGUOUS points/thread. R7/R8-proven
// INDEX-tracking structure (coords-in-loop variants spill: R6/R9).
// 8 waves halve the update-issue cost (the biggest per-iter term);
// xyz kept as ONE float4 LDS array so the dependent centroid fetch is
// a single ds_read_b128 broadcast. Zero VMEM in the loop (sout staged).
// Selection arithmetic bit-identical to R2..R8: contract-off,
// d = dx*dx + dy*dy; d = d + dz*dz; fmin; strict > in lane, lowest
// ballot lane, earlier-wave-on-tie => np.argmax smallest index.
// ------------------------------------------------------------------
__global__ __launch_bounds__(kFT) void fps_kernel(const float* __restrict__ xyz,
                                                  float* __restrict__ new_xyz) {
#pragma clang fp contract(off)
  const int b = blockIdx.x;
  const int tid = threadIdx.x;
  const int w = tid >> 6;
  const int lane = tid & 63;
  const float* xb = xyz + (size_t)b * kN * 3;

  __shared__ float4 sxyz[kN];                       // 64 KB (x,y,z,0)
  __shared__ float sout[kS * 3];                    // 12 KB staged output
  __shared__ __align__(16) float pV[2][kFW];        // per-wave max, parity
  __shared__ __align__(16) int   pI[2][kFW];        // per-wave cand idx

  float px[kFP], py[kFP], pz[kFP], dist[kFP];
#pragma unroll
  for (int j = 0; j < kFP; ++j) {
    const int p = tid * kFP + j;               // contiguous chunk
    const float x = xb[p * 3 + 0];
    const float y = xb[p * 3 + 1];
    const float z = xb[p * 3 + 2];
    px[j] = x; py[j] = y; pz[j] = z;
    sxyz[p] = make_float4(x, y, z, 0.f);
    dist[j] = 1e10f;
  }
  float cx = xb[0], cy = xb[1], cz = xb[2];  // farthest starts at index 0
  __syncthreads();

  for (int t = 0; t < kS; ++t) {
    if (tid == 0) {
      sout[t * 3 + 0] = cx; sout[t * 3 + 1] = cy; sout[t * 3 + 2] = cz;
    }
    // --- update + per-lane argmax (strict > keeps smallest j)
    float lv = -1.0f;
    int bi = 0;
#pragma unroll
    for (int j = 0; j < kFP; ++j) {
      const float dx = px[j] - cx, dy = py[j] - cy, dz = pz[j] - cz;
      float d = dx * dx + dy * dy;
      d = d + dz * dz;
      const float dd = fminf(dist[j], d);
      dist[j] = dd;
      if (dd > lv) { lv = dd; bi = tid * kFP + j; }
    }
    // --- wave max via DPP (VALU pipe), index via ballot+readlane
    const float wm = wave_max_dpp(lv);
    const float sM = __int_as_float(__builtin_amdgcn_readlane(__float_as_int(wm), 63));
    const unsigned long long mk = __ballot(lv == sM);
    const int fl = __builtin_ctzll(mk);        // lowest lane = smallest index
    const int cand = __builtin_amdgcn_readlane(bi, fl);
    const int par = t & 1;
    if (lane == 0) { pV[par][w] = sM; pI[par][w] = cand; }
    __syncthreads();
    const float4 v0 = *(const float4*)&pV[par][0];   // ds_read_b128
    const float4 v1 = *(const float4*)&pV[par][4];
    const int4 i0 = *(const int4*)&pI[par][0];
    const int4 i1 = *(const int4*)&pI[par][4];
    float bv = v0.x; int bci = i0.x;
    if (v0.y > bv) { bv = v0.y; bci = i0.y; }  // tie -> earlier wave = smaller idx
    if (v0.z > bv) { bv = v0.z; bci = i0.z; }
    if (v0.w > bv) { bv = v0.w; bci = i0.w; }
    if (v1.x > bv) { bv = v1.x; bci = i1.x; }
    if (v1.y > bv) { bv = v1.y; bci = i1.y; }
    if (v1.z > bv) { bv = v1.z; bci = i1.z; }
    if (v1.w > bv) { bv = v1.w; bci = i1.w; }
    const float4 c = sxyz[bci];                // one ds_read_b128 broadcast
    cx = c.x; cy = c.y; cz = c.z;
  }
  __syncthreads();
  float* ob = new_xyz + (size_t)b * kS * 3;
  for (int e = tid; e < kS * 3; e += kFT) ob[e] = sout[e];  // coalesced once
}

// ------------------------------------------------------------------
// Ball query (unchanged)
// ------------------------------------------------------------------
__global__ __launch_bounds__(256) void ball_kernel(const float* __restrict__ xyz,
                                                   const float* __restrict__ new_xyz,
                                                   int* __restrict__ idx) {
  const int g = blockIdx.x * 4 + (threadIdx.x >> 6);
  const int lane = threadIdx.x & 63;
  const int b = g >> 10;
  const float* xb = xyz + (size_t)b * kN * 3;
  const double sx = (double)new_xyz[(size_t)g * 3 + 0];
  const double sy = (double)new_xyz[(size_t)g * 3 + 1];
  const double sz = (double)new_xyz[(size_t)g * 3 + 2];
  const double s2 = sx * sx + sy * sy + sz * sz;
  int have = 0, first = -1;
  int* out = idx + (size_t)g * kK;
  for (int c = 0; c < kN; c += 64) {
    const int p = c + lane;
    const double px = (double)xb[p * 3 + 0];
    const double py = (double)xb[p * 3 + 1];
    const double pz = (double)xb[p * 3 + 2];
    const double p2 = px * px + py * py + pz * pz;
    const double dot = sx * px + sy * py + sz * pz;
    const double d = -2.0 * dot + s2 + p2;
    const bool elig = !(d > kR2d);
    const unsigned long long mask = __ballot(elig);
    if (first < 0 && mask) first = c + __builtin_ctzll(mask);
    const int pos = have + __popcll(mask & ((1ull << lane) - 1ull));
    if (elig && pos < kK) out[pos] = p;
    have += __popcll(mask);
    if (have >= kK) break;
  }
  if (have < kK) {
    if (lane >= have && lane < kK) out[lane] = first;
  }
}

// ------------------------------------------------------------------
// Split w0/w1/w2 into B-fragment-ordered (hi,lo) arrays (unchanged)
// ------------------------------------------------------------------
__global__ __launch_bounds__(256) void wsplit_kernel(const float* __restrict__ w0,
                                                     const float* __restrict__ w1,
                                                     const float* __restrict__ w2,
                                                     unsigned short* __restrict__ whiF,
                                                     unsigned short* __restrict__ wloF) {
  const int gid = blockIdx.x * 256 + threadIdx.x;   // 88*64 = 5632 total
  const int lane = gid & 63;
  const int f = gid >> 6;
  const int quad = lane >> 4, l15 = lane & 15;
  const float* src;
  int kt, nt, nstride;
  if (f < 8) { src = w0; kt = f >> 2; nt = f & 3; nstride = C1; }
  else if (f < 24) { const int fl = f - 8; src = w1; kt = fl >> 3; nt = fl & 7; nstride = C2; }
  else { const int fl = f - 24; src = w2; kt = fl >> 4; nt = fl & 15; nstride = C3; }
  const int k0 = kt * 32 + quad * 8;
  const int n = nt * 16 + l15;
#pragma unroll
  for (int j = 0; j < 8; ++j) {
    const float x = src[(size_t)(k0 + j) * nstride + n];
    unsigned hi, lo;
    split_bf16(x, hi, lo);
    whiF[(size_t)gid * 8 + j] = (unsigned short)hi;
    wloF[(size_t)gid * 8 + j] = (unsigned short)lo;
  }
}

// ------------------------------------------------------------------
// gather (VECTORIZED): points part via float4 — 16 consecutive lanes
// read one sample's contiguous 64-float row (256 B segments).
// ------------------------------------------------------------------
__device__ __forceinline__ void gather_packed(int g, const float* __restrict__ xyz,
                                              const float* __restrict__ points,
                                              const float* __restrict__ new_xyz,
                                              const int* __restrict__ idx,
                                              unsigned* fsp) {
  const int b = g >> 10;
  const float* xb = xyz + (size_t)b * kN * 3;
  const float* pb = points + (size_t)b * kN * kD;
  const int* ig = idx + (size_t)g * kK;
  const int tid = threadIdx.x;
#pragma unroll
  for (int it = 0; it < 2; ++it) {
    const int e = tid + it * 256;          // 512 items: (r, c4)
    const int r = e >> 4, c4 = e & 15;
    const int i = ig[r];
    const float4 v = *(const float4*)(pb + (size_t)i * kD + c4 * 4);
    const int cb = 3 + c4 * 4;
    fsp[(cb + 0) * kLS + r] = pack_sb(v.x);
    fsp[(cb + 1) * kLS + r] = pack_sb(v.y);
    fsp[(cb + 2) * kLS + r] = pack_sb(v.z);
    fsp[(cb + 3) * kLS + r] = pack_sb(v.w);
  }
  if (tid < 96) {
    const int c = tid >> 5, r = tid & 31;
    const int i = ig[r];
    const float v = xb[i * 3 + c] - new_xyz[(size_t)g * 3 + c];
    fsp[c * kLS + r] = pack_sb(v);
  }
}

// L1 via MFMA: K=64 through matrix cores + channels 64..66 VALU tail.
__device__ __forceinline__ void l1_mfma(const unsigned* fsp,
                                        const unsigned short* __restrict__ whiF,
                                        const unsigned short* __restrict__ wloF,
                                        const float* __restrict__ w0,
                                        const float* __restrict__ b0,
                                        int mt, int nh, int quad, int l15, int lane,
                                        f32x4 out[2]) {
  short8 ah[2], al[2];
#pragma unroll
  for (int ks = 0; ks < 2; ++ks)
    load_afrag(fsp, ks * 32, mt * 16, quad, l15, ah[ks], al[ks]);
#pragma unroll
  for (int nt2 = 0; nt2 < 2; ++nt2) {
    const int nt = nh * 2 + nt2;
    const int n = nt * 16 + l15;
    f32x4 acc = {0.f, 0.f, 0.f, 0.f};
#pragma unroll
    for (int ks = 0; ks < 2; ++ks)
      acc = mfma3(ah[ks], al[ks], whiF, wloF, ((size_t)(ks * 4 + nt) * 64 + lane) * 8, acc);
#pragma unroll
    for (int c = 64; c < 67; ++c) {
      const float wv0 = w0[(size_t)c * C1 + n];
#pragma unroll
      for (int r = 0; r < 4; ++r) {
        const float x = unpack_sb(fsp[c * kLS + mt * 16 + quad * 4 + r]);
        acc[r] += x * wv0;
      }
    }
    const float bb = b0[n];
#pragma unroll
    for (int r = 0; r < 4; ++r) acc[r] += bb;
    out[nt2] = acc;
  }
}

// ------------------------------------------------------------------
// stats1: gather + L1(MFMA) -> partials. If x1p != nullptr, persist
// packed pre-BN L1 output (coalesced, for stats2 to skip gather+L1).
// ------------------------------------------------------------------
__global__ __launch_bounds__(256) void stats1_kernel(
    const float* __restrict__ xyz, const float* __restrict__ points,
    const float* __restrict__ new_xyz, const int* __restrict__ idx,
    const float* __restrict__ w0, const float* __restrict__ b0,
    const unsigned short* __restrict__ whiF, const unsigned short* __restrict__ wloF,
    float* __restrict__ P, unsigned* __restrict__ x1p) {
  __shared__ unsigned fsp[C0 * kLS];
  __shared__ unsigned x1s[32 * kX1S];
  __shared__ float redS[C1 * 2], redQ[C1 * 2];
  const int g = blockIdx.x;
  const int tid = threadIdx.x;
  gather_packed(g, xyz, points, new_xyz, idx, fsp);
  __syncthreads();
  const int wv = tid >> 6, lane = tid & 63;
  const int mt = wv & 1, nh = wv >> 1;
  const int quad = lane >> 4, l15 = lane & 15;
  f32x4 acc1[2];
  l1_mfma(fsp, whiF, wloF, w0, b0, mt, nh, quad, l15, lane, acc1);
#pragma unroll
  for (int nt2 = 0; nt2 < 2; ++nt2) {
    const int n = (nh * 2 + nt2) * 16 + l15;
    const f32x4 a = acc1[nt2];
    if (x1p) {
      const int m0 = mt * 16 + quad * 4;
      x1s[(m0 + 0) * kX1S + n] = pack_sb(a[0]);
      x1s[(m0 + 1) * kX1S + n] = pack_sb(a[1]);
      x1s[(m0 + 2) * kX1S + n] = pack_sb(a[2]);
      x1s[(m0 + 3) * kX1S + n] = pack_sb(a[3]);
    }
    float s = a[0] + a[1] + a[2] + a[3];
    float q = a[0] * a[0] + a[1] * a[1] + a[2] * a[2] + a[3] * a[3];
    s += __shfl_xor(s, 16); s += __shfl_xor(s, 32);
    q += __shfl_xor(q, 16); q += __shfl_xor(q, 32);
    if (quad == 0) { redS[n * 2 + mt] = s; redQ[n * 2 + mt] = q; }
  }
  __syncthreads();
  if (x1p) {
#pragma unroll
    for (int i = 0; i < 8; ++i) {
      const int f = tid + i * 256;
      const int m = f >> 6, n = f & 63;
      x1p[(size_t)g * 2048 + f] = x1s[m * kX1S + n];   // coalesced
    }
  }
  if (tid < C1) {
    P[(size_t)g * 2 * C1 + tid] = redS[tid * 2] + redS[tid * 2 + 1];
    P[(size_t)g * 2 * C1 + C1 + tid] = redQ[tid * 2] + redQ[tid * 2 + 1];
  }
}

// ------------------------------------------------------------------
// stats2: if x1p present, read persisted x1 (skip gather+L1); else
// gather + L1. Then BN0/relu/pack + L2(MFMA) -> partials (+x2 persist).
// ------------------------------------------------------------------
__global__ __launch_bounds__(256) void stats2_kernel(
    const float* __restrict__ xyz, const float* __restrict__ points,
    const float* __restrict__ new_xyz, const int* __restrict__ idx,
    const float* __restrict__ w0, const float* __restrict__ b0, const float* __restrict__ ab0,
    const float* __restrict__ b1,
    const unsigned short* __restrict__ whiF, const unsigned short* __restrict__ wloF,
    float* __restrict__ P, const unsigned* __restrict__ x1p, unsigned* __restrict__ x2p) {
  __shared__ unsigned fsp[C0 * kLS];
  __shared__ unsigned y1p[C1 * kLS];
  __shared__ unsigned x2s[32 * kXS];
  __shared__ float sab0[2 * C1];
  __shared__ float redS[C2 * 2], redQ[C2 * 2];
  const int g = blockIdx.x;
  const int tid = threadIdx.x;
  const int wv = tid >> 6, lane = tid & 63;
  const int mt = wv & 1, nh = wv >> 1;
  const int quad = lane >> 4, l15 = lane & 15;
  if (x1p) {
    if (tid < 2 * C1) sab0[tid] = ab0[tid];
    __syncthreads();
#pragma unroll
    for (int i = 0; i < 8; ++i) {
      const int f = tid + i * 256;
      const int m = f >> 6, n = f & 63;
      const float x = unpack_sb(x1p[(size_t)g * 2048 + f]);   // coalesced
      const float y = fmaxf(x * sab0[n * 2 + 0] + sab0[n * 2 + 1], 0.f);
      y1p[n * kLS + m] = pack_sb(y);
    }
  } else {
    gather_packed(g, xyz, points, new_xyz, idx, fsp);
    __syncthreads();
    f32x4 acc1[2];
    l1_mfma(fsp, whiF, wloF, w0, b0, mt, nh, quad, l15, lane, acc1);
#pragma unroll
    for (int nt2 = 0; nt2 < 2; ++nt2) {
      const int n = (nh * 2 + nt2) * 16 + l15;
      const float a = ab0[n * 2 + 0], c = ab0[n * 2 + 1];
#pragma unroll
      for (int r = 0; r < 4; ++r) {
        const float y = fmaxf(acc1[nt2][r] * a + c, 0.f);
        y1p[n * kLS + mt * 16 + quad * 4 + r] = pack_sb(y);
      }
    }
  }
  __syncthreads();
  {
    short8 ah[2], al[2];
#pragma unroll
    for (int ks = 0; ks < 2; ++ks)
      load_afrag(y1p, ks * 32, mt * 16, quad, l15, ah[ks], al[ks]);
#pragma unroll
    for (int nt2 = 0; nt2 < 4; ++nt2) {
      const int nt = nh * 4 + nt2;
      const int n = nt * 16 + l15;
      f32x4 acc = {0.f, 0.f, 0.f, 0.f};
#pragma unroll
      for (int ks = 0; ks < 2; ++ks)
        acc = mfma3(ah[ks], al[ks], whiF, wloF, ((size_t)(8 + ks * 8 + nt) * 64 + lane) * 8, acc);
      const float bb = b1[n];
      const float v0 = acc[0] + bb, v1 = acc[1] + bb, v2 = acc[2] + bb, v3 = acc[3] + bb;
      if (x2p) {
        const int m0 = mt * 16 + quad * 4;
        x2s[(m0 + 0) * kXS + n] = pack_sb(v0);
        x2s[(m0 + 1) * kXS + n] = pack_sb(v1);
        x2s[(m0 + 2) * kXS + n] = pack_sb(v2);
        x2s[(m0 + 3) * kXS + n] = pack_sb(v3);
      }
      float s = v0 + v1 + v2 + v3;
      float q = v0 * v0 + v1 * v1 + v2 * v2 + v3 * v3;
      s += __shfl_xor(s, 16); s += __shfl_xor(s, 32);
      q += __shfl_xor(q, 16); q += __shfl_xor(q, 32);
      if (quad == 0) { redS[n * 2 + mt] = s; redQ[n * 2 + mt] = q; }
    }
  }
  __syncthreads();
  if (x2p) {
#pragma unroll
    for (int i = 0; i < 16; ++i) {
      const int f = tid + i * 256;
      const int m = f >> 7, n = f & 127;
      x2p[(size_t)g * 4096 + f] = x2s[m * kXS + n];   // coalesced 256B/wave
    }
  }
  if (tid < C2) {
    P[(size_t)g * 2 * C2 + tid] = redS[tid * 2] + redS[tid * 2 + 1];
    P[(size_t)g * 2 * C2 + C2 + tid] = redQ[tid * 2] + redQ[tid * 2 + 1];
  }
}

// ------------------------------------------------------------------
// stats3 (FALLBACK): gather + L1 + L2 + L3 all via MFMA
// ------------------------------------------------------------------
__global__ __launch_bounds__(256) void stats3_kernel(
    const float* __restrict__ xyz, const float* __restrict__ points,
    const float* __restrict__ new_xyz, const int* __restrict__ idx,
    const float* __restrict__ w0, const float* __restrict__ b0, const float* __restrict__ ab0,
    const float* __restrict__ b1, const float* __restrict__ ab1,
    const float* __restrict__ b2,
    const unsigned short* __restrict__ whiF, const unsigned short* __restrict__ wloF,
    float* __restrict__ P, float* __restrict__ maxv, float* __restrict__ minv) {
  __shared__ unsigned fsp[C0 * kLS];
  __shared__ unsigned y1p[C1 * kLS];
  __shared__ unsigned y2p[C2 * kLS];
  __shared__ float redS[C3 * 2], redQ[C3 * 2], redM[C3 * 2], redN[C3 * 2];
  const int g = blockIdx.x;
  const int tid = threadIdx.x;
  gather_packed(g, xyz, points, new_xyz, idx, fsp);
  __syncthreads();
  const int wv = tid >> 6, lane = tid & 63;
  const int mt = wv & 1, nh = wv >> 1;
  const int quad = lane >> 4, l15 = lane & 15;
  {
    f32x4 acc1[2];
    l1_mfma(fsp, whiF, wloF, w0, b0, mt, nh, quad, l15, lane, acc1);
#pragma unroll
    for (int nt2 = 0; nt2 < 2; ++nt2) {
      const int n = (nh * 2 + nt2) * 16 + l15;
      const float a = ab0[n * 2 + 0], c = ab0[n * 2 + 1];
#pragma unroll
      for (int r = 0; r < 4; ++r) {
        const float y = fmaxf(acc1[nt2][r] * a + c, 0.f);
        y1p[n * kLS + mt * 16 + quad * 4 + r] = pack_sb(y);
      }
    }
  }
  __syncthreads();
  {
    short8 ah[2], al[2];
#pragma unroll
    for (int ks = 0; ks < 2; ++ks)
      load_afrag(y1p, ks * 32, mt * 16, quad, l15, ah[ks], al[ks]);
#pragma unroll
    for (int nt2 = 0; nt2 < 4; ++nt2) {
      const int nt = nh * 4 + nt2;
      const int n = nt * 16 + l15;
      f32x4 acc = {0.f, 0.f, 0.f, 0.f};
#pragma unroll
      for (int ks = 0; ks < 2; ++ks)
        acc = mfma3(ah[ks], al[ks], whiF, wloF, ((size_t)(8 + ks * 8 + nt) * 64 + lane) * 8, acc);
      const float bb = b1[n];
      const float a = ab1[n * 2 + 0], c = ab1[n * 2 + 1];
#pragma unroll
      for (int r = 0; r < 4; ++r) {
        const float y = fmaxf((acc[r] + bb) * a + c, 0.f);
        y2p[n * kLS + mt * 16 + quad * 4 + r] = pack_sb(y);
      }
    }
  }
  __syncthreads();
  {
    short8 ah[4], al[4];
#pragma unroll
    for (int ks = 0; ks < 4; ++ks)
      load_afrag(y2p, ks * 32, mt * 16, quad, l15, ah[ks], al[ks]);
#pragma unroll
    for (int nt2 = 0; nt2 < 8; ++nt2) {
      const int nt = nh * 8 + nt2;
      f32x4 acc = {0.f, 0.f, 0.f, 0.f};
#pragma unroll
      for (int ks = 0; ks < 4; ++ks)
        acc = mfma3(ah[ks], al[ks], whiF, wloF, ((size_t)(24 + ks * 16 + nt) * 64 + lane) * 8, acc);
      const int n = nt * 16 + l15;
      const float bn = b2[n];
      const float v0 = acc[0] + bn, v1 = acc[1] + bn, v2 = acc[2] + bn, v3 = acc[3] + bn;
      float s = v0 + v1 + v2 + v3;
      float q = v0 * v0 + v1 * v1 + v2 * v2 + v3 * v3;
      float mx = fmaxf(fmaxf(v0, v1), fmaxf(v2, v3));
      float mn = fminf(fminf(v0, v1), fminf(v2, v3));
      s += __shfl_xor(s, 16); s += __shfl_xor(s, 32);
      q += __shfl_xor(q, 16); q += __shfl_xor(q, 32);
      mx = fmaxf(mx, __shfl_xor(mx, 16)); mx = fmaxf(mx, __shfl_xor(mx, 32));
      mn = fminf(mn, __shfl_xor(mn, 16)); mn = fminf(mn, __shfl_xor(mn, 32));
      if (quad == 0) {
        redS[n * 2 + mt] = s; redQ[n * 2 + mt] = q;
        redM[n * 2 + mt] = mx; redN[n * 2 + mt] = mn;
      }
    }
  }
  __syncthreads();
  {
    const int ch = tid;
    P[(size_t)g * 2 * C3 + ch] = redS[ch * 2] + redS[ch * 2 + 1];
    P[(size_t)g * 2 * C3 + C3 + ch] = redQ[ch * 2] + redQ[ch * 2 + 1];
    maxv[(size_t)g * C3 + ch] = fmaxf(redM[ch * 2], redM[ch * 2 + 1]);
    minv[(size_t)g * C3 + ch] = fminf(redN[ch * 2], redN[ch * 2 + 1]);
  }
}

// ------------------------------------------------------------------
// stats3p (PERSIST): read packed x2, BN1+relu -> y2p LDS, then L3
// via MFMA; partials + fused maxpool.
// ------------------------------------------------------------------
__global__ __launch_bounds__(256) void stats3p_kernel(
    const unsigned* __restrict__ x2p, const float* __restrict__ ab1,
    const float* __restrict__ b2,
    const unsigned short* __restrict__ whiF, const unsigned short* __restrict__ wloF,
    float* __restrict__ P, float* __restrict__ maxv, float* __restrict__ minv) {
  __shared__ unsigned y2p[C2 * kLS];
  __shared__ float sab[2 * C2];
  __shared__ float redS[C3 * 2], redQ[C3 * 2], redM[C3 * 2], redN[C3 * 2];
  const int g = blockIdx.x;
  const int tid = threadIdx.x;
  sab[tid] = ab1[tid];            // 256 floats = 2*C2
  __syncthreads();
#pragma unroll
  for (int i = 0; i < 16; ++i) {
    const int f = tid + i * 256;
    const int m = f >> 7, n = f & 127;
    const unsigned pk = x2p[(size_t)g * 4096 + f];   // coalesced 256B/wave
    const float x = unpack_sb(pk);
    const float y = fmaxf(x * sab[n * 2 + 0] + sab[n * 2 + 1], 0.f);
    y2p[n * kLS + m] = pack_sb(y);
  }
  __syncthreads();
  const int wv = tid >> 6, lane = tid & 63;
  const int mt = wv & 1, nh = wv >> 1;
  const int quad = lane >> 4, l15 = lane & 15;
  {
    short8 ah[4], al[4];
#pragma unroll
    for (int ks = 0; ks < 4; ++ks)
      load_afrag(y2p, ks * 32, mt * 16, quad, l15, ah[ks], al[ks]);
#pragma unroll
    for (int nt2 = 0; nt2 < 8; ++nt2) {
      const int nt = nh * 8 + nt2;
      f32x4 acc = {0.f, 0.f, 0.f, 0.f};
#pragma unroll
      for (int ks = 0; ks < 4; ++ks)
        acc = mfma3(ah[ks], al[ks], whiF, wloF, ((size_t)(24 + ks * 16 + nt) * 64 + lane) * 8, acc);
      const int n = nt * 16 + l15;
      const float bn = b2[n];
      const float v0 = acc[0] + bn, v1 = acc[1] + bn, v2 = acc[2] + bn, v3 = acc[3] + bn;
      float s = v0 + v1 + v2 + v3;
      float q = v0 * v0 + v1 * v1 + v2 * v2 + v3 * v3;
      float mx = fmaxf(fmaxf(v0, v1), fmaxf(v2, v3));
      float mn = fminf(fminf(v0, v1), fminf(v2, v3));
      s += __shfl_xor(s, 16); s += __shfl_xor(s, 32);
      q += __shfl_xor(q, 16); q += __shfl_xor(q, 32);
      mx = fmaxf(mx, __shfl_xor(mx, 16)); mx = fmaxf(mx, __shfl_xor(mx, 32));
      mn = fminf(mn, __shfl_xor(mn, 16)); mn = fminf(mn, __shfl_xor(mn, 32));
      if (quad == 0) {
        redS[n * 2 + mt] = s; redQ[n * 2 + mt] = q;
        redM[n * 2 + mt] = mx; redN[n * 2 + mt] = mn;
      }
    }
  }
  __syncthreads();
  {
    const int ch = tid;
    P[(size_t)g * 2 * C3 + ch] = redS[ch * 2] + redS[ch * 2 + 1];
    P[(size_t)g * 2 * C3 + C3 + ch] = redQ[ch * 2] + redQ[ch * 2 + 1];
    maxv[(size_t)g * C3 + ch] = fmaxf(redM[ch * 2], redM[ch * 2 + 1]);
    minv[(size_t)g * C3 + ch] = fminf(redN[ch * 2], redN[ch * 2 + 1]);
  }
}

// ------------------------------------------------------------------
// reduce / final (unchanged)
// ------------------------------------------------------------------
__global__ __launch_bounds__(256) void reduce_kernel(const float* __restrict__ P, int CH,
                                                     const float* __restrict__ gamma,
                                                     const float* __restrict__ beta,
                                                     float* __restrict__ ab) {
  const int ch = blockIdx.x;
  float s = 0.f, q = 0.f;
  for (int i = threadIdx.x; i < kG; i += 256) {
    s += P[(size_t)i * 2 * CH + ch];
    q += P[(size_t)i * 2 * CH + CH + ch];
  }
#pragma unroll
  for (int off = 32; off > 0; off >>= 1) {
    s += __shfl_down(s, off);
    q += __shfl_down(q, off);
  }
  __shared__ float ss[4], qs[4];
  if ((threadIdx.x & 63) == 0) { ss[threadIdx.x >> 6] = s; qs[threadIdx.x >> 6] = q; }
  __syncthreads();
  if (threadIdx.x == 0) {
    s = ss[0] + ss[1] + ss[2] + ss[3];
    q = qs[0] + qs[1] + qs[2] + qs[3];
    const float mean = s / kRowCount;
    float var = q / kRowCount - mean * mean;
    var = fmaxf(var, 0.f);
    const float a = gamma[ch] * (1.0f / sqrtf(var + kEps));
    const float c = beta[ch] - mean * a;
    ab[ch * 2 + 0] = a;
    ab[ch * 2 + 1] = c;
  }
}

__global__ __launch_bounds__(256) void final_kernel(const float* __restrict__ ab2,
                                                    const float* __restrict__ maxv,
                                                    const float* __restrict__ minv,
                                                    float* __restrict__ out) {
  const int e = blockIdx.x * 256 + threadIdx.x;
  const int ch = e & (C3 - 1);
  const float a = ab2[ch * 2 + 0];
  const float c = ab2[ch * 2 + 1];
  const float m = (a >= 0.f) ? maxv[e] : minv[e];
  out[e] = fmaxf(a * m + c, 0.f);
}

extern "C" void kernel_launch(void* const* d_in, const int* in_sizes, int n_in,
                              void* d_out, int out_size, void* d_ws, size_t ws_size,
                              hipStream_t stream) {
  const float* xyz = (const float*)d_in[0];
  const float* points = (const float*)d_in[1];
  const float* w0 = (const float*)d_in[2];
  const float* b0 = (const float*)d_in[3];
  const float* g0 = (const float*)d_in[4];
  const float* bt0 = (const float*)d_in[5];
  const float* w1 = (const float*)d_in[6];
  const float* b1 = (const float*)d_in[7];
  const float* g1 = (const float*)d_in[8];
  const float* bt1 = (const float*)d_in[9];
  const float* w2 = (const float*)d_in[10];
  const float* b2 = (const float*)d_in[11];
  const float* g2 = (const float*)d_in[12];
  const float* bt2 = (const float*)d_in[13];

  float* out_xyz = (float*)d_out;               // (16,1024,3)
  float* out_pts = out_xyz + (size_t)kG * 3;    // (16,1024,256)

  char* ws = (char*)d_ws;
  int* idx = (int*)ws;                                      // 2 MB
  float* P = (float*)(ws + (size_t)kG * kK * sizeof(int));  // 33.5 MB (sized for C3)
  float* maxv = P + (size_t)kG * 2 * C3;                    // 16.8 MB
  float* minv = maxv + (size_t)kG * C3;                     // 16.8 MB
  float* ab0 = minv + (size_t)kG * C3;
  float* ab1 = ab0 + 2 * C1;
  float* ab2 = ab1 + 2 * C2;
  unsigned short* whiF = (unsigned short*)(ab2 + 2 * C3);   // 88 KB (16B aligned)
  unsigned short* wloF = whiF + (size_t)kNF * 512;          // 88 KB
  unsigned* x2p = (unsigned*)(wloF + (size_t)kNF * 512);    // 268 MB (optional)
  unsigned* x1p = x2p + (size_t)kG * 4096;                  // 134 MB (optional)
  const size_t needed1 = (size_t)((char*)(x2p + (size_t)kG * 4096) - ws);
  const size_t needed2 = (size_t)((char*)(x1p + (size_t)kG * 2048) - ws);
  const bool persist = ws_size >= needed1;                   // constant across calls
  const bool persist2 = ws_size >= needed2;
  unsigned* x2arg = persist ? x2p : nullptr;
  unsigned* x1arg = persist2 ? x1p : nullptr;

  wsplit_kernel<<<kNF / 4, 256, 0, stream>>>(w0, w1, w2, whiF, wloF);
  fps_kernel<<<kNB, kFT, 0, stream>>>(xyz, out_xyz);
  ball_kernel<<<kG / 4, 256, 0, stream>>>(xyz, out_xyz, idx);
  stats1_kernel<<<kG, 256, 0, stream>>>(xyz, points, out_xyz, idx, w0, b0, whiF, wloF,
                                        P, x1arg);
  reduce_kernel<<<C1, 256, 0, stream>>>(P, C1, g0, bt0, ab0);
  stats2_kernel<<<kG, 256, 0, stream>>>(xyz, points, out_xyz, idx, w0, b0, ab0, b1,
                                        whiF, wloF, P, x1arg, x2arg);
  reduce_kernel<<<C2, 256, 0, stream>>>(P, C2, g1, bt1, ab1);
  if (persist) {
    stats3p_kernel<<<kG, 256, 0, stream>>>(x2p, ab1, b2, whiF, wloF, P, maxv, minv);
  } else {
    stats3_kernel<<<kG, 256, 0, stream>>>(xyz, points, out_xyz, idx, w0, b0, ab0,
                                          b1, ab1, b2, whiF, wloF, P, maxv, minv);
  }
  reduce_kernel<<<C3, 256, 0, stream>>>(P, C3, g2, bt2, ab2);
  final_kernel<<<(kG * C3) / 256, 256, 0, stream>>>(ab2, maxv, minv, out_pts);
}